// Round 11
// baseline (217.222 us; speedup 1.0000x reference)
//
#include <hip/hip_runtime.h>
#include <hip/hip_bf16.h>
#include <math.h>

#define EPS_F 1e-7f

constexpr int Bn = 128, Sn = 1024, Dn = 256, ATTn = 128, QDn = 128;
constexpr int Mn = Bn * Sn;          // 131072 rows
constexpr int BM = 128;              // rows per block (8 waves x 16 rows)
constexpr int NBLK = Mn / BM;        // 1024 blocks
constexpr int NJ = ATTn / 16;        // 8 column fragments

typedef short short8 __attribute__((ext_vector_type(8)));
typedef float f32x4  __attribute__((ext_vector_type(4)));

// Exact truncation split: f = hi + r exactly (hi = top-16-bit float),
// lo = bf16_rne(r). A_hi*B_hi + A_hi*B_lo + A_lo*B_hi ~ 2^-17 relative.
__device__ inline void split_bf(float f, ushort& hi, ushort& lo) {
    uint fb = __float_as_uint(f);
    hi = (ushort)(fb >> 16);
    float hf = __uint_as_float(fb & 0xffff0000u);
    float lf = f - hf;                       // exact
    __hip_bfloat16 lb = __float2bfloat16(lf);
    __builtin_memcpy(&lo, &lb, 2);
}

__device__ inline float tanh_fast(float x) {
    float cx = fminf(9.0f, fmaxf(-9.0f, x));
    float e = __builtin_amdgcn_exp2f(cx * 2.8853900817779268f);  // e^{2x}
    return (e - 1.0f) * __builtin_amdgcn_rcpf(e + 1.0f);
}

// async global->LDS, 16B per lane. LDS dest is wave-uniform base + lane*16;
// the GLOBAL source is per-lane.
__device__ inline void gload_lds16(const void* g, void* lds_base) {
    __builtin_amdgcn_global_load_lds(
        (const __attribute__((address_space(1))) unsigned int*)g,
        (__attribute__((address_space(3))) unsigned int*)lds_base, 16, 0, 0);
}

#define MFMA_BF16 __builtin_amdgcn_mfma_f32_16x16x32_bf16

// ---------------- ws layout (bytes) ----------------
// [0,512)              u (128 f32)
// [512,66048)          Bhi (4096 chunks x 8 bf16)
// [66048,131584)       Blo
// [131584,1180160)     P   (1024 blk * 256 d f32)
// [1180160,1184256)    den (1024 f32)

// Merged prep: block 0 computes u = W_u @ query; blocks 1..16 build the
// MFMA-B-fragment-ordered bf16 hi/lo copies of W.
// Fragment (ks,j): lane l holds col = 16j+(l&15), k = 32ks+(l>>4)*8+i.
__global__ __launch_bounds__(256) void k_prep(
    const float* __restrict__ Wu, const float* __restrict__ q,
    float* __restrict__ u,
    const float* __restrict__ W,
    ushort* __restrict__ Bhi, ushort* __restrict__ Blo)
{
    if (blockIdx.x == 0) {
        __shared__ float qs[QDn];
        int t = threadIdx.x;
        if (t < QDn) qs[t] = q[t];
        __syncthreads();
        if (t < ATTn) {
            float acc = 0.f;
            #pragma unroll 8
            for (int j = 0; j < QDn; ++j) acc += Wu[t * QDn + j] * qs[j];
            u[t] = acc;
        }
        return;
    }
    int gid  = (blockIdx.x - 1) * 256 + threadIdx.x;   // 0..4095
    int lane = gid & 63;
    int j    = (gid >> 6) & 7;
    int ks   = gid >> 9;
    int col  = j * 16 + (lane & 15);
    int kb   = ks * 32 + (lane >> 4) * 8;
    #pragma unroll
    for (int i = 0; i < 8; ++i) {
        float f = W[(size_t)(kb + i) * ATTn + col];
        ushort h, l;
        split_bf(f, h, l);
        size_t idx = (size_t)gid * 8 + i;
        Bhi[idx] = h; Blo[idx] = l;
    }
}

// One k-step (K=32). B for this kstep resident in buf[KS&1] (hi 512 chunks,
// lo 512 chunks). Stage next kstep's B first (async, hidden under MFMAs),
// then convert kv -> bf16 hi/lo, refill kv ring 4 ahead, run 8 fragments x 3
// split-MFMAs with j+1 LDS prefetch. One barrier at the end.
template<int KS>
__device__ __forceinline__ void kstep(
    float4* smem, const ushort* __restrict__ Bhi, const ushort* __restrict__ Blo,
    const float* kb, float4 (&kv)[4][2], f32x4 (&acc)[NJ],
    int lane, int t, int w)
{
    const float4* buf = smem + (KS & 1) * 1024;
    if (KS + 1 < 8) {   // stage next kstep's 16 KB into the other buffer
        float4* nbuf = smem + ((KS + 1) & 1) * 1024;
        gload_lds16(Bhi + ((size_t)((KS + 1) * 512 + t)) * 8, nbuf + w * 64);
        gload_lds16(Blo + ((size_t)((KS + 1) * 512 + t)) * 8, nbuf + 512 + w * 64);
    }
    constexpr int S = KS & 3;
    short8 ah, al;
    {
        float4 v0 = kv[S][0], v1 = kv[S][1];
        float f[8] = {v0.x, v0.y, v0.z, v0.w, v1.x, v1.y, v1.z, v1.w};
        #pragma unroll
        for (int i = 0; i < 8; ++i) {
            ushort h, l;
            split_bf(f[i], h, l);
            ah[i] = (short)h; al[i] = (short)l;
        }
    }
    if (KS + 4 < 8) {   // 4-deep kv prefetch
        kv[S][0] = *(const float4*)(kb + (KS + 4) * 32);
        kv[S][1] = *(const float4*)(kb + (KS + 4) * 32 + 4);
    }
    const float4* Bh = buf + lane;
    const float4* Bl = buf + 512 + lane;
    short8 bh = *(const short8*)Bh;
    short8 bl = *(const short8*)Bl;
    #pragma unroll
    for (int j = 0; j < NJ; ++j) {
        short8 nbh, nbl;
        if (j + 1 < NJ) {
            nbh = *(const short8*)(Bh + (j + 1) * 64);
            nbl = *(const short8*)(Bl + (j + 1) * 64);
        }
        acc[j] = MFMA_BF16(ah, bh, acc[j], 0, 0, 0);
        acc[j] = MFMA_BF16(ah, bl, acc[j], 0, 0, 0);
        acc[j] = MFMA_BF16(al, bh, acc[j], 0, 0, 0);
        bh = nbh; bl = nbl;
    }
    __syncthreads();   // next-B landed (vmcnt drain) + all waves done with buf
}

// Fused: scores (bf16-split MFMA, K=256, N=128) + partial weighted sums.
// 8 waves x 16 rows (BM=128); B per-kstep double-buffered in 32 KB LDS ->
// 4 blocks/CU, 32 waves/CU (8/SIMD). VGPR target: 64.
__global__ __launch_bounds__(512, 8) void k_scores(
    const float*  __restrict__ key,
    const ushort* __restrict__ Bhi, const ushort* __restrict__ Blo,
    const float*  __restrict__ bias, const float* __restrict__ u,
    const int*    __restrict__ mask,
    float* __restrict__ P, float* __restrict__ den)
{
    __shared__ float4 smem[2048];        // 32 KB: 2 x (8 KB hi + 8 KB lo)
    float*  esp   = (float*)smem;        // [128] scores (aliased after loop)
    float4* partp = smem + 64;           // [8][64] float4 partials

    const int t    = threadIdx.x;        // 0..511
    const int lane = t & 63;
    const int w    = t >> 6;             // wave 0..7 -> rows w*16..w*16+15
    const int gb   = blockIdx.x;
    const int row0 = gb * BM;
    const int l15  = lane & 15;
    const int lg   = lane >> 4;

    const float* kb = key + (size_t)(row0 + w * 16 + l15) * Dn + lg * 8;

    f32x4 acc[NJ];
    #pragma unroll
    for (int j = 0; j < NJ; ++j) acc[j] = (f32x4){0.f, 0.f, 0.f, 0.f};

    // kv ring: k-steps 0..3
    float4 kv[4][2];
    #pragma unroll
    for (int s = 0; s < 4; ++s) {
        kv[s][0] = *(const float4*)(kb + s * 32);
        kv[s][1] = *(const float4*)(kb + s * 32 + 4);
    }

    // stage kstep 0's B into buf0
    gload_lds16(Bhi + (size_t)t * 8, smem + w * 64);
    gload_lds16(Blo + (size_t)t * 8, smem + 512 + w * 64);
    __syncthreads();

    kstep<0>(smem, Bhi, Blo, kb, kv, acc, lane, t, w);
    kstep<1>(smem, Bhi, Blo, kb, kv, acc, lane, t, w);
    kstep<2>(smem, Bhi, Blo, kb, kv, acc, lane, t, w);
    kstep<3>(smem, Bhi, Blo, kb, kv, acc, lane, t, w);
    kstep<4>(smem, Bhi, Blo, kb, kv, acc, lane, t, w);
    kstep<5>(smem, Bhi, Blo, kb, kv, acc, lane, t, w);
    kstep<6>(smem, Bhi, Blo, kb, kv, acc, lane, t, w);
    kstep<7>(smem, Bhi, Blo, kb, kv, acc, lane, t, w);
    // last kstep's __syncthreads: B dead; smem reusable

    // Epilogue: s(row) = sum_col tanh(acc+bias)*u; e = exp(s)*mask.
    // C/D layout: col = 16j + l15, row(frag-local) = lg*4 + reg.
    float s4[4] = {0.f, 0.f, 0.f, 0.f};
    #pragma unroll
    for (int j = 0; j < NJ; ++j) {
        int col = j * 16 + l15;
        float bv = bias[col], uvv = u[col];
        #pragma unroll
        for (int reg = 0; reg < 4; ++reg)
            s4[reg] += tanh_fast(acc[j][reg] + bv) * uvv;
    }
    #pragma unroll
    for (int reg = 0; reg < 4; ++reg) {
        float s = s4[reg];
        s += __shfl_xor(s, 1);
        s += __shfl_xor(s, 2);
        s += __shfl_xor(s, 4);
        s += __shfl_xor(s, 8);
        if (l15 == 0) {
            int rl = w * 16 + lg * 4 + reg;
            esp[rl] = __builtin_amdgcn_exp2f(s * 1.4426950408889634f)
                      * (float)mask[row0 + rl];
        }
    }
    __syncthreads();

    // block-partial denominator (128 scores)
    if (t < 64) {
        float v = esp[t] + esp[t + 64];
        #pragma unroll
        for (int m = 1; m < 64; m <<= 1) v += __shfl_xor(v, m);
        if (t == 0) den[gb] = v;
    }

    // phase 2: wave w sums its 16 rows over all d (tile is L2/L3-hot).
    {
        const float4* kt = (const float4*)(key + (size_t)(row0 + w * 16) * Dn);
        float4 a2 = make_float4(0.f, 0.f, 0.f, 0.f);
        #pragma unroll 4
        for (int s2 = 0; s2 < 16; ++s2) {
            float wv   = esp[w * 16 + s2];
            float4 kvv = kt[(size_t)s2 * 64 + lane];
            a2.x += wv * kvv.x; a2.y += wv * kvv.y;
            a2.z += wv * kvv.z; a2.w += wv * kvv.w;
        }
        partp[w * 64 + lane] = a2;
    }
    __syncthreads();

    if (t < 64) {
        float4 o = partp[t];
        #pragma unroll
        for (int wv = 1; wv < 8; ++wv) {
            float4 p = partp[wv * 64 + t];
            o.x += p.x; o.y += p.y; o.z += p.z; o.w += p.w;
        }
        *(float4*)(P + (size_t)gb * Dn + t * 4) = o;
    }
}

// combine 8 block-partials per batch, normalize.
__global__ __launch_bounds__(256) void k_final(const float* __restrict__ P,
        const float* __restrict__ den, float* __restrict__ out) {
    int b = blockIdx.x, t = threadIdx.x;
    float dtot = 0.f;
    #pragma unroll
    for (int k = 0; k < 8; ++k) dtot += den[b * 8 + k];
    float o = 0.f;
    #pragma unroll
    for (int k = 0; k < 8; ++k) o += P[(size_t)(b * 8 + k) * Dn + t];
    out[(size_t)b * Dn + t] = o / (dtot + EPS_F);
}

extern "C" void kernel_launch(void* const* d_in, const int* in_sizes, int n_in,
                              void* d_out, int out_size, void* d_ws, size_t ws_size,
                              hipStream_t stream) {
    const float* key   = (const float*)d_in[0];
    const float* query = (const float*)d_in[1];
    const int*   mask  = (const int*)d_in[2];
    const float* W     = (const float*)d_in[3];
    const float* bias  = (const float*)d_in[4];
    const float* Wu    = (const float*)d_in[5];
    float* out = (float*)d_out;

    char* ws = (char*)d_ws;
    float*  u   = (float*)(ws);
    ushort* Bhi = (ushort*)(ws + 512);
    ushort* Blo = (ushort*)(ws + 66048);
    float*  Pp  = (float*)(ws + 131584);
    float*  den = (float*)(ws + 1180160);

    hipLaunchKernelGGL(k_prep,   dim3(17),   dim3(256), 0, stream, Wu, query, u, W, Bhi, Blo);
    hipLaunchKernelGGL(k_scores, dim3(NBLK), dim3(512), 0, stream,
                       key, Bhi, Blo, bias, u, mask, Pp, den);
    hipLaunchKernelGGL(k_final,  dim3(Bn),   dim3(256), 0, stream, Pp, den, out);
}

// Round 12
// 58.356 us; speedup vs baseline: 3.7224x; 3.7224x over previous
//
#include <hip/hip_runtime.h>
#include <hip/hip_bf16.h>
#include <math.h>

#define EPS_F 1e-7f

constexpr int Bn = 128, Sn = 1024, Dn = 256, ATTn = 128, QDn = 128;
constexpr int Mn = Bn * Sn;          // 131072 rows
constexpr int BM = 128;              // rows per block (8 waves x 16 rows)
constexpr int NBLK = Mn / BM;        // 1024 blocks
constexpr int NJ = ATTn / 16;        // 8 column fragments

typedef short short8 __attribute__((ext_vector_type(8)));
typedef float f32x4  __attribute__((ext_vector_type(4)));

// Exact truncation split: f = hi + r exactly (hi = top-16-bit float),
// lo = bf16_rne(r). A_hi*B_hi + A_hi*B_lo + A_lo*B_hi ~ 2^-17 relative.
__device__ inline void split_bf(float f, ushort& hi, ushort& lo) {
    uint fb = __float_as_uint(f);
    hi = (ushort)(fb >> 16);
    float hf = __uint_as_float(fb & 0xffff0000u);
    float lf = f - hf;                       // exact
    __hip_bfloat16 lb = __float2bfloat16(lf);
    __builtin_memcpy(&lo, &lb, 2);
}

__device__ inline float tanh_fast(float x) {
    float cx = fminf(9.0f, fmaxf(-9.0f, x));
    float e = __builtin_amdgcn_exp2f(cx * 2.8853900817779268f);  // e^{2x}
    return (e - 1.0f) * __builtin_amdgcn_rcpf(e + 1.0f);
}

// async global->LDS, 16B per lane. LDS dest is wave-uniform base + lane*16;
// the GLOBAL source is per-lane.
__device__ inline void gload_lds16(const void* g, void* lds_base) {
    __builtin_amdgcn_global_load_lds(
        (const __attribute__((address_space(1))) unsigned int*)g,
        (__attribute__((address_space(3))) unsigned int*)lds_base, 16, 0, 0);
}

#define MFMA_BF16 __builtin_amdgcn_mfma_f32_16x16x32_bf16

// ---------------- ws layout (bytes) ----------------
// [0,512)              u (128 f32)
// [512,66048)          Bhi (4096 chunks x 8 bf16)
// [66048,131584)       Blo
// [131584,1180160)     P   (1024 blk * 256 d f32)
// [1180160,1184256)    den (1024 f32)

// Merged prep: block 0 computes u = W_u @ query; blocks 1..16 build the
// MFMA-B-fragment-ordered bf16 hi/lo copies of W.
// Fragment (ks,j): lane l holds col = 16j+(l&15), k = 32ks+(l>>4)*8+i.
__global__ __launch_bounds__(256) void k_prep(
    const float* __restrict__ Wu, const float* __restrict__ q,
    float* __restrict__ u,
    const float* __restrict__ W,
    ushort* __restrict__ Bhi, ushort* __restrict__ Blo)
{
    if (blockIdx.x == 0) {
        __shared__ float qs[QDn];
        int t = threadIdx.x;
        if (t < QDn) qs[t] = q[t];
        __syncthreads();
        if (t < ATTn) {
            float acc = 0.f;
            #pragma unroll 8
            for (int j = 0; j < QDn; ++j) acc += Wu[t * QDn + j] * qs[j];
            u[t] = acc;
        }
        return;
    }
    int gid  = (blockIdx.x - 1) * 256 + threadIdx.x;   // 0..4095
    int lane = gid & 63;
    int j    = (gid >> 6) & 7;
    int ks   = gid >> 9;
    int col  = j * 16 + (lane & 15);
    int kb   = ks * 32 + (lane >> 4) * 8;
    #pragma unroll
    for (int i = 0; i < 8; ++i) {
        float f = W[(size_t)(kb + i) * ATTn + col];
        ushort h, l;
        split_bf(f, h, l);
        size_t idx = (size_t)gid * 8 + i;
        Bhi[idx] = h; Blo[idx] = l;
    }
}

// Stage one quarter-K of B (2 ksteps: hi+lo, 32 KB) into dst.
// Layout: [ks2][hp][512 chunks]; chunk c = i*512 + t.
__device__ __forceinline__ void stage_quarter(
    float4* dst, const ushort* __restrict__ Bhi,
    const ushort* __restrict__ Blo, int q, int t, int w)
{
    #pragma unroll
    for (int i = 0; i < 4; ++i) {
        int c   = i * 512 + t;           // 0..2047
        int ks2 = c >> 10;               // wave-uniform (i>>1)
        int hp  = (c >> 9) & 1;          // wave-uniform (i&1)
        int idx = c & 511;
        const ushort* src = (hp ? Blo : Bhi)
                          + ((size_t)((q * 2 + ks2) * 512 + idx)) * 8;
        gload_lds16(src, dst + (i * 512 + w * 64));
    }
}

// One k-step (K=32): convert kv -> bf16 hi/lo, refill kv ring 4 ahead,
// 8 column fragments x 3 split-MFMAs with j+1 LDS prefetch. No barrier here.
template<int KS>
__device__ __forceinline__ void kstep(
    float4* smem, const float* kb,
    float4 (&kv)[4][2], f32x4 (&acc)[NJ], int lane)
{
    const float4* buf = smem + ((KS >> 1) & 1) * 2048;   // quarter buffer
    constexpr int S  = KS & 3;                           // kv ring slot
    constexpr int S2 = KS & 1;                           // kstep within quarter
    short8 ah, al;
    {
        float4 v0 = kv[S][0], v1 = kv[S][1];
        float f[8] = {v0.x, v0.y, v0.z, v0.w, v1.x, v1.y, v1.z, v1.w};
        #pragma unroll
        for (int i = 0; i < 8; ++i) {
            ushort h, l;
            split_bf(f[i], h, l);
            ah[i] = (short)h; al[i] = (short)l;
        }
    }
    if (KS + 4 < 8) {   // 4-deep kv prefetch
        kv[S][0] = *(const float4*)(kb + (KS + 4) * 32);
        kv[S][1] = *(const float4*)(kb + (KS + 4) * 32 + 4);
    }
    const float4* Bh = buf + S2 * 1024 + lane;
    const float4* Bl = Bh + 512;
    short8 bh = *(const short8*)Bh;
    short8 bl = *(const short8*)Bl;
    #pragma unroll
    for (int j = 0; j < NJ; ++j) {
        short8 nbh, nbl;
        if (j + 1 < NJ) {
            nbh = *(const short8*)(Bh + (j + 1) * 64);
            nbl = *(const short8*)(Bl + (j + 1) * 64);
        }
        acc[j] = MFMA_BF16(ah, bh, acc[j], 0, 0, 0);
        acc[j] = MFMA_BF16(ah, bl, acc[j], 0, 0, 0);
        acc[j] = MFMA_BF16(al, bh, acc[j], 0, 0, 0);
        bh = nbh; bl = nbl;
    }
}

// Fused: scores (bf16-split MFMA, K=256, N=128) + partial weighted sums.
// 8 waves x 16 rows (BM=128). B quarter-K double-buffered (2 x 32 KB):
// next quarter's stage is issued BEFORE the current quarter's compute, so
// the per-quarter barrier finds the data already landed (no exposed stall).
// 64 KB LDS -> 2 blocks/CU = 16 waves/CU.
__global__ __launch_bounds__(512, 4) void k_scores(
    const float*  __restrict__ key,
    const ushort* __restrict__ Bhi, const ushort* __restrict__ Blo,
    const float*  __restrict__ bias, const float* __restrict__ u,
    const int*    __restrict__ mask,
    float* __restrict__ P, float* __restrict__ den)
{
    __shared__ float4 smem[4096];        // 64 KB: 2 x 32 KB quarter buffers
    float*  esp   = (float*)smem;        // [128] scores (aliased after loop)
    float4* partp = smem + 64;           // [8][64] float4 partials

    const int t    = threadIdx.x;        // 0..511
    const int lane = t & 63;
    const int w    = t >> 6;             // wave 0..7 -> rows w*16..w*16+15
    const int gb   = blockIdx.x;
    const int row0 = gb * BM;
    const int l15  = lane & 15;
    const int lg   = lane >> 4;

    const float* kb = key + (size_t)(row0 + w * 16 + l15) * Dn + lg * 8;

    f32x4 acc[NJ];
    #pragma unroll
    for (int j = 0; j < NJ; ++j) acc[j] = (f32x4){0.f, 0.f, 0.f, 0.f};

    // kv ring: k-steps 0..3
    float4 kv[4][2];
    #pragma unroll
    for (int s = 0; s < 4; ++s) {
        kv[s][0] = *(const float4*)(kb + s * 32);
        kv[s][1] = *(const float4*)(kb + s * 32 + 4);
    }

    stage_quarter(smem, Bhi, Blo, 0, t, w);          // quarter 0 -> buf0
    __syncthreads();

    stage_quarter(smem + 2048, Bhi, Blo, 1, t, w);   // Q1 -> buf1 (hidden)
    kstep<0>(smem, kb, kv, acc, lane);
    kstep<1>(smem, kb, kv, acc, lane);
    __syncthreads();                                 // Q1 landed; buf0 free

    stage_quarter(smem, Bhi, Blo, 2, t, w);          // Q2 -> buf0 (hidden)
    kstep<2>(smem, kb, kv, acc, lane);
    kstep<3>(smem, kb, kv, acc, lane);
    __syncthreads();

    stage_quarter(smem + 2048, Bhi, Blo, 3, t, w);   // Q3 -> buf1 (hidden)
    kstep<4>(smem, kb, kv, acc, lane);
    kstep<5>(smem, kb, kv, acc, lane);
    __syncthreads();

    kstep<6>(smem, kb, kv, acc, lane);
    kstep<7>(smem, kb, kv, acc, lane);
    __syncthreads();                     // B dead; smem reusable

    // Epilogue: s(row) = sum_col tanh(acc+bias)*u; e = exp(s)*mask.
    // C/D layout: col = 16j + l15, row(frag-local) = lg*4 + reg.
    float s4[4] = {0.f, 0.f, 0.f, 0.f};
    #pragma unroll
    for (int j = 0; j < NJ; ++j) {
        int col = j * 16 + l15;
        float bv = bias[col], uvv = u[col];
        #pragma unroll
        for (int reg = 0; reg < 4; ++reg)
            s4[reg] += tanh_fast(acc[j][reg] + bv) * uvv;
    }
    #pragma unroll
    for (int reg = 0; reg < 4; ++reg) {
        float s = s4[reg];
        s += __shfl_xor(s, 1);
        s += __shfl_xor(s, 2);
        s += __shfl_xor(s, 4);
        s += __shfl_xor(s, 8);
        if (l15 == 0) {
            int rl = w * 16 + lg * 4 + reg;
            esp[rl] = __builtin_amdgcn_exp2f(s * 1.4426950408889634f)
                      * (float)mask[row0 + rl];
        }
    }
    __syncthreads();

    // block-partial denominator (128 scores)
    if (t < 64) {
        float v = esp[t] + esp[t + 64];
        #pragma unroll
        for (int m = 1; m < 64; m <<= 1) v += __shfl_xor(v, m);
        if (t == 0) den[gb] = v;
    }

    // phase 2: wave w sums its 16 rows over all d (tile is L2/L3-hot).
    {
        const float4* kt = (const float4*)(key + (size_t)(row0 + w * 16) * Dn);
        float4 a2 = make_float4(0.f, 0.f, 0.f, 0.f);
        #pragma unroll 4
        for (int s2 = 0; s2 < 16; ++s2) {
            float wv   = esp[w * 16 + s2];
            float4 kvv = kt[(size_t)s2 * 64 + lane];
            a2.x += wv * kvv.x; a2.y += wv * kvv.y;
            a2.z += wv * kvv.z; a2.w += wv * kvv.w;
        }
        partp[w * 64 + lane] = a2;
    }
    __syncthreads();

    if (t < 64) {
        float4 o = partp[t];
        #pragma unroll
        for (int wv = 1; wv < 8; ++wv) {
            float4 p = partp[wv * 64 + t];
            o.x += p.x; o.y += p.y; o.z += p.z; o.w += p.w;
        }
        *(float4*)(P + (size_t)gb * Dn + t * 4) = o;
    }
}

// combine 8 block-partials per batch, normalize.
__global__ __launch_bounds__(256) void k_final(const float* __restrict__ P,
        const float* __restrict__ den, float* __restrict__ out) {
    int b = blockIdx.x, t = threadIdx.x;
    float dtot = 0.f;
    #pragma unroll
    for (int k = 0; k < 8; ++k) dtot += den[b * 8 + k];
    float o = 0.f;
    #pragma unroll
    for (int k = 0; k < 8; ++k) o += P[(size_t)(b * 8 + k) * Dn + t];
    out[(size_t)b * Dn + t] = o / (dtot + EPS_F);
}

extern "C" void kernel_launch(void* const* d_in, const int* in_sizes, int n_in,
                              void* d_out, int out_size, void* d_ws, size_t ws_size,
                              hipStream_t stream) {
    const float* key   = (const float*)d_in[0];
    const float* query = (const float*)d_in[1];
    const int*   mask  = (const int*)d_in[2];
    const float* W     = (const float*)d_in[3];
    const float* bias  = (const float*)d_in[4];
    const float* Wu    = (const float*)d_in[5];
    float* out = (float*)d_out;

    char* ws = (char*)d_ws;
    float*  u   = (float*)(ws);
    ushort* Bhi = (ushort*)(ws + 512);
    ushort* Blo = (ushort*)(ws + 66048);
    float*  Pp  = (float*)(ws + 131584);
    float*  den = (float*)(ws + 1180160);

    hipLaunchKernelGGL(k_prep,   dim3(17),   dim3(256), 0, stream, Wu, query, u, W, Bhi, Blo);
    hipLaunchKernelGGL(k_scores, dim3(NBLK), dim3(512), 0, stream,
                       key, Bhi, Blo, bias, u, mask, Pp, den);
    hipLaunchKernelGGL(k_final,  dim3(Bn),   dim3(256), 0, stream, Pp, den, out);
}

// Round 13
// 57.880 us; speedup vs baseline: 3.7530x; 1.0082x over previous
//
#include <hip/hip_runtime.h>
#include <hip/hip_bf16.h>
#include <math.h>

#define EPS_F 1e-7f

constexpr int Bn = 128, Sn = 1024, Dn = 256, ATTn = 128, QDn = 128;
constexpr int Mn = Bn * Sn;          // 131072 rows
constexpr int BM = 128;              // rows per block (8 waves x 16 rows)
constexpr int NBLK = Mn / BM;        // 1024 blocks
constexpr int NJ = ATTn / 16;        // 8 column fragments

typedef short short8 __attribute__((ext_vector_type(8)));
typedef float f32x4  __attribute__((ext_vector_type(4)));

// Exact truncation split: f = hi + r exactly (hi = top-16-bit float),
// lo = bf16_rne(r). A_hi*B_hi + A_hi*B_lo + A_lo*B_hi ~ 2^-17 relative.
__device__ inline void split_bf(float f, ushort& hi, ushort& lo) {
    uint fb = __float_as_uint(f);
    hi = (ushort)(fb >> 16);
    float hf = __uint_as_float(fb & 0xffff0000u);
    float lf = f - hf;                       // exact
    __hip_bfloat16 lb = __float2bfloat16(lf);
    __builtin_memcpy(&lo, &lb, 2);
}

__device__ inline float tanh_fast(float x) {
    float cx = fminf(9.0f, fmaxf(-9.0f, x));
    float e = __builtin_amdgcn_exp2f(cx * 2.8853900817779268f);  // e^{2x}
    return (e - 1.0f) * __builtin_amdgcn_rcpf(e + 1.0f);
}

// async global->LDS, 16B per lane. LDS dest is wave-uniform base + lane*16;
// the GLOBAL source is per-lane.
__device__ inline void gload_lds16(const void* g, void* lds_base) {
    __builtin_amdgcn_global_load_lds(
        (const __attribute__((address_space(1))) unsigned int*)g,
        (__attribute__((address_space(3))) unsigned int*)lds_base, 16, 0, 0);
}

#define MFMA_BF16 __builtin_amdgcn_mfma_f32_16x16x32_bf16

// ---------------- ws layout (bytes) ----------------
// [0,512)              u (128 f32)
// [512,66048)          Bhi (4096 chunks x 8 bf16)
// [66048,131584)       Blo
// [131584,1180160)     P   (1024 blk * 256 d f32)
// [1180160,1184256)    den (1024 f32)

// Merged prep: block 0 computes u = W_u @ query; blocks 1..16 build the
// MFMA-B-fragment-ordered bf16 hi/lo copies of W.
// Fragment (ks,j): lane l holds col = 16j+(l&15), k = 32ks+(l>>4)*8+i.
__global__ __launch_bounds__(256) void k_prep(
    const float* __restrict__ Wu, const float* __restrict__ q,
    float* __restrict__ u,
    const float* __restrict__ W,
    ushort* __restrict__ Bhi, ushort* __restrict__ Blo)
{
    if (blockIdx.x == 0) {
        __shared__ float qs[QDn];
        int t = threadIdx.x;
        if (t < QDn) qs[t] = q[t];
        __syncthreads();
        if (t < ATTn) {
            float acc = 0.f;
            #pragma unroll 8
            for (int j = 0; j < QDn; ++j) acc += Wu[t * QDn + j] * qs[j];
            u[t] = acc;
        }
        return;
    }
    int gid  = (blockIdx.x - 1) * 256 + threadIdx.x;   // 0..4095
    int lane = gid & 63;
    int j    = (gid >> 6) & 7;
    int ks   = gid >> 9;
    int col  = j * 16 + (lane & 15);
    int kb   = ks * 32 + (lane >> 4) * 8;
    #pragma unroll
    for (int i = 0; i < 8; ++i) {
        float f = W[(size_t)(kb + i) * ATTn + col];
        ushort h, l;
        split_bf(f, h, l);
        size_t idx = (size_t)gid * 8 + i;
        Bhi[idx] = h; Blo[idx] = l;
    }
}

// Stage one quarter-K of B (2 ksteps: hi+lo, 32 KB) into dst.
// Layout: [ks2][hp][512 chunks]; chunk c = i*512 + t.
__device__ __forceinline__ void stage_quarter(
    float4* dst, const ushort* __restrict__ Bhi,
    const ushort* __restrict__ Blo, int q, int t, int w)
{
    #pragma unroll
    for (int i = 0; i < 4; ++i) {
        int c   = i * 512 + t;           // 0..2047
        int ks2 = c >> 10;               // wave-uniform (i>>1)
        int hp  = (c >> 9) & 1;          // wave-uniform (i&1)
        int idx = c & 511;
        const ushort* src = (hp ? Blo : Bhi)
                          + ((size_t)((q * 2 + ks2) * 512 + idx)) * 8;
        gload_lds16(src, dst + (i * 512 + w * 64));
    }
}

// One k-step (K=32): convert kv -> bf16 hi/lo, refill kv ring 4 ahead,
// 8 column fragments x 3 split-MFMAs with a 3-DEEP circular B prefetch
// (reads for j+3 issued before MFMAs of j -> issue distance >= LDS latency).
template<int KS>
__device__ __forceinline__ void kstep(
    float4* smem, const float* kb,
    float4 (&kv)[4][2], f32x4 (&acc)[NJ], int lane)
{
    const float4* buf = smem + ((KS >> 1) & 1) * 2048;   // quarter buffer
    constexpr int S  = KS & 3;                           // kv ring slot
    constexpr int S2 = KS & 1;                           // kstep within quarter
    short8 ah, al;
    {
        float4 v0 = kv[S][0], v1 = kv[S][1];
        float f[8] = {v0.x, v0.y, v0.z, v0.w, v1.x, v1.y, v1.z, v1.w};
        #pragma unroll
        for (int i = 0; i < 8; ++i) {
            ushort h, l;
            split_bf(f[i], h, l);
            ah[i] = (short)h; al[i] = (short)l;
        }
    }
    if (KS + 4 < 8) {   // 4-deep kv prefetch
        kv[S][0] = *(const float4*)(kb + (KS + 4) * 32);
        kv[S][1] = *(const float4*)(kb + (KS + 4) * 32 + 4);
    }
    const float4* Bh = buf + S2 * 1024 + lane;
    const float4* Bl = Bh + 512;
    short8 bh[3], bl[3];
    bh[0] = *(const short8*)(Bh);
    bl[0] = *(const short8*)(Bl);
    bh[1] = *(const short8*)(Bh + 64);
    bl[1] = *(const short8*)(Bl + 64);
    bh[2] = *(const short8*)(Bh + 128);
    bl[2] = *(const short8*)(Bl + 128);
    #pragma unroll
    for (int j = 0; j < NJ; ++j) {
        const int slot = j % 3;          // static after unroll
        short8 cbh = bh[slot], cbl = bl[slot];
        if (j + 3 < NJ) {
            bh[slot] = *(const short8*)(Bh + (j + 3) * 64);
            bl[slot] = *(const short8*)(Bl + (j + 3) * 64);
        }
        acc[j] = MFMA_BF16(ah, cbh, acc[j], 0, 0, 0);
        acc[j] = MFMA_BF16(ah, cbl, acc[j], 0, 0, 0);
        acc[j] = MFMA_BF16(al, cbh, acc[j], 0, 0, 0);
    }
}

// Fused: scores (bf16-split MFMA, K=256, N=128) + partial weighted sums.
// 8 waves x 16 rows (BM=128). B quarter-K double-buffered (2 x 32 KB),
// next quarter's stage issued BEFORE the current quarter's compute.
// 64 KB LDS -> 2 blocks/CU = 16 waves/CU (4/SIMD). waves_per_eu(4,4)
// pins the register budget at 128 so the allocator keeps the pipeline.
__global__ __launch_bounds__(512)
__attribute__((amdgpu_waves_per_eu(4, 4))) void k_scores(
    const float*  __restrict__ key,
    const ushort* __restrict__ Bhi, const ushort* __restrict__ Blo,
    const float*  __restrict__ bias, const float* __restrict__ u,
    const int*    __restrict__ mask,
    float* __restrict__ P, float* __restrict__ den)
{
    __shared__ float4 smem[4096];        // 64 KB: 2 x 32 KB quarter buffers
    float*  esp   = (float*)smem;        // [128] scores (aliased after loop)
    float4* partp = smem + 64;           // [8][64] float4 partials

    const int t    = threadIdx.x;        // 0..511
    const int lane = t & 63;
    const int w    = t >> 6;             // wave 0..7 -> rows w*16..w*16+15
    const int gb   = blockIdx.x;
    const int row0 = gb * BM;
    const int l15  = lane & 15;
    const int lg   = lane >> 4;

    const float* kb = key + (size_t)(row0 + w * 16 + l15) * Dn + lg * 8;

    f32x4 acc[NJ];
    #pragma unroll
    for (int j = 0; j < NJ; ++j) acc[j] = (f32x4){0.f, 0.f, 0.f, 0.f};

    // kv ring: k-steps 0..3
    float4 kv[4][2];
    #pragma unroll
    for (int s = 0; s < 4; ++s) {
        kv[s][0] = *(const float4*)(kb + s * 32);
        kv[s][1] = *(const float4*)(kb + s * 32 + 4);
    }

    stage_quarter(smem, Bhi, Blo, 0, t, w);          // quarter 0 -> buf0
    __syncthreads();

    stage_quarter(smem + 2048, Bhi, Blo, 1, t, w);   // Q1 -> buf1 (hidden)
    kstep<0>(smem, kb, kv, acc, lane);
    kstep<1>(smem, kb, kv, acc, lane);
    __syncthreads();                                 // Q1 landed; buf0 free

    stage_quarter(smem, Bhi, Blo, 2, t, w);          // Q2 -> buf0 (hidden)
    kstep<2>(smem, kb, kv, acc, lane);
    kstep<3>(smem, kb, kv, acc, lane);
    __syncthreads();

    stage_quarter(smem + 2048, Bhi, Blo, 3, t, w);   // Q3 -> buf1 (hidden)
    kstep<4>(smem, kb, kv, acc, lane);
    kstep<5>(smem, kb, kv, acc, lane);
    __syncthreads();

    kstep<6>(smem, kb, kv, acc, lane);
    kstep<7>(smem, kb, kv, acc, lane);
    __syncthreads();                     // B dead; smem reusable

    // Epilogue: s(row) = sum_col tanh(acc+bias)*u; e = exp(s)*mask.
    // C/D layout: col = 16j + l15, row(frag-local) = lg*4 + reg.
    float s4[4] = {0.f, 0.f, 0.f, 0.f};
    #pragma unroll
    for (int j = 0; j < NJ; ++j) {
        int col = j * 16 + l15;
        float bv = bias[col], uvv = u[col];
        #pragma unroll
        for (int reg = 0; reg < 4; ++reg)
            s4[reg] += tanh_fast(acc[j][reg] + bv) * uvv;
    }
    #pragma unroll
    for (int reg = 0; reg < 4; ++reg) {
        float s = s4[reg];
        s += __shfl_xor(s, 1);
        s += __shfl_xor(s, 2);
        s += __shfl_xor(s, 4);
        s += __shfl_xor(s, 8);
        if (l15 == 0) {
            int rl = w * 16 + lg * 4 + reg;
            esp[rl] = __builtin_amdgcn_exp2f(s * 1.4426950408889634f)
                      * (float)mask[row0 + rl];
        }
    }
    __syncthreads();

    // block-partial denominator (128 scores)
    if (t < 64) {
        float v = esp[t] + esp[t + 64];
        #pragma unroll
        for (int m = 1; m < 64; m <<= 1) v += __shfl_xor(v, m);
        if (t == 0) den[gb] = v;
    }

    // phase 2: wave w sums its 16 rows over all d (tile is L2/L3-hot).
    {
        const float4* kt = (const float4*)(key + (size_t)(row0 + w * 16) * Dn);
        float4 a2 = make_float4(0.f, 0.f, 0.f, 0.f);
        #pragma unroll 4
        for (int s2 = 0; s2 < 16; ++s2) {
            float wv   = esp[w * 16 + s2];
            float4 kvv = kt[(size_t)s2 * 64 + lane];
            a2.x += wv * kvv.x; a2.y += wv * kvv.y;
            a2.z += wv * kvv.z; a2.w += wv * kvv.w;
        }
        partp[w * 64 + lane] = a2;
    }
    __syncthreads();

    if (t < 64) {
        float4 o = partp[t];
        #pragma unroll
        for (int wv = 1; wv < 8; ++wv) {
            float4 p = partp[wv * 64 + t];
            o.x += p.x; o.y += p.y; o.z += p.z; o.w += p.w;
        }
        *(float4*)(P + (size_t)gb * Dn + t * 4) = o;
    }
}

// combine 8 block-partials per batch, normalize.
__global__ __launch_bounds__(256) void k_final(const float* __restrict__ P,
        const float* __restrict__ den, float* __restrict__ out) {
    int b = blockIdx.x, t = threadIdx.x;
    float dtot = 0.f;
    #pragma unroll
    for (int k = 0; k < 8; ++k) dtot += den[b * 8 + k];
    float o = 0.f;
    #pragma unroll
    for (int k = 0; k < 8; ++k) o += P[(size_t)(b * 8 + k) * Dn + t];
    out[(size_t)b * Dn + t] = o / (dtot + EPS_F);
}

extern "C" void kernel_launch(void* const* d_in, const int* in_sizes, int n_in,
                              void* d_out, int out_size, void* d_ws, size_t ws_size,
                              hipStream_t stream) {
    const float* key   = (const float*)d_in[0];
    const float* query = (const float*)d_in[1];
    const int*   mask  = (const int*)d_in[2];
    const float* W     = (const float*)d_in[3];
    const float* bias  = (const float*)d_in[4];
    const float* Wu    = (const float*)d_in[5];
    float* out = (float*)d_out;

    char* ws = (char*)d_ws;
    float*  u   = (float*)(ws);
    ushort* Bhi = (ushort*)(ws + 512);
    ushort* Blo = (ushort*)(ws + 66048);
    float*  Pp  = (float*)(ws + 131584);
    float*  den = (float*)(ws + 1180160);

    hipLaunchKernelGGL(k_prep,   dim3(17),   dim3(256), 0, stream, Wu, query, u, W, Bhi, Blo);
    hipLaunchKernelGGL(k_scores, dim3(NBLK), dim3(512), 0, stream,
                       key, Bhi, Blo, bias, u, mask, Pp, den);
    hipLaunchKernelGGL(k_final,  dim3(Bn),   dim3(256), 0, stream, Pp, den, out);
}

// Round 14
// 57.129 us; speedup vs baseline: 3.8023x; 1.0131x over previous
//
#include <hip/hip_runtime.h>
#include <hip/hip_bf16.h>
#include <math.h>

#define EPS_F 1e-7f

constexpr int Bn = 128, Sn = 1024, Dn = 256, ATTn = 128, QDn = 128;
constexpr int Mn = Bn * Sn;          // 131072 rows
constexpr int BM = 128;              // rows per block (8 waves x 16 rows)
constexpr int NBLK = Mn / BM;        // 1024 blocks
constexpr int NJ = ATTn / 16;        // 8 column fragments

typedef short short8 __attribute__((ext_vector_type(8)));
typedef float f32x4  __attribute__((ext_vector_type(4)));

// Exact truncation split: f = hi + r exactly (hi = top-16-bit float),
// lo = bf16_rne(r). A_hi*B_hi + A_hi*B_lo + A_lo*B_hi ~ 2^-17 relative.
__device__ inline void split_bf(float f, ushort& hi, ushort& lo) {
    uint fb = __float_as_uint(f);
    hi = (ushort)(fb >> 16);
    float hf = __uint_as_float(fb & 0xffff0000u);
    float lf = f - hf;                       // exact
    __hip_bfloat16 lb = __float2bfloat16(lf);
    __builtin_memcpy(&lo, &lb, 2);
}

__device__ inline float tanh_fast(float x) {
    float cx = fminf(9.0f, fmaxf(-9.0f, x));
    float e = __builtin_amdgcn_exp2f(cx * 2.8853900817779268f);  // e^{2x}
    return (e - 1.0f) * __builtin_amdgcn_rcpf(e + 1.0f);
}

// async global->LDS, 16B per lane. LDS dest is wave-uniform base + lane*16;
// the GLOBAL source is per-lane.
__device__ inline void gload_lds16(const void* g, void* lds_base) {
    __builtin_amdgcn_global_load_lds(
        (const __attribute__((address_space(1))) unsigned int*)g,
        (__attribute__((address_space(3))) unsigned int*)lds_base, 16, 0, 0);
}

#define MFMA_BF16 __builtin_amdgcn_mfma_f32_16x16x32_bf16

// ---------------- ws layout (bytes) ----------------
// [0,512)              u (128 f32)
// [512,66048)          Bhi (4096 chunks x 8 bf16)
// [66048,131584)       Blo
// [131584,1180160)     P   (1024 blk * 256 d f32)
// [1180160,1184256)    den (1024 f32)

// Merged prep: block 0 computes u = W_u @ query; blocks 1..16 build the
// MFMA-B-fragment-ordered bf16 hi/lo copies of W.
// Fragment (ks,j): lane l holds col = 16j+(l&15), k = 32ks+(l>>4)*8+i.
__global__ __launch_bounds__(256) void k_prep(
    const float* __restrict__ Wu, const float* __restrict__ q,
    float* __restrict__ u,
    const float* __restrict__ W,
    ushort* __restrict__ Bhi, ushort* __restrict__ Blo)
{
    if (blockIdx.x == 0) {
        __shared__ float qs[QDn];
        int t = threadIdx.x;
        if (t < QDn) qs[t] = q[t];
        __syncthreads();
        if (t < ATTn) {
            float acc = 0.f;
            #pragma unroll 8
            for (int j = 0; j < QDn; ++j) acc += Wu[t * QDn + j] * qs[j];
            u[t] = acc;
        }
        return;
    }
    int gid  = (blockIdx.x - 1) * 256 + threadIdx.x;   // 0..4095
    int lane = gid & 63;
    int j    = (gid >> 6) & 7;
    int ks   = gid >> 9;
    int col  = j * 16 + (lane & 15);
    int kb   = ks * 32 + (lane >> 4) * 8;
    #pragma unroll
    for (int i = 0; i < 8; ++i) {
        float f = W[(size_t)(kb + i) * ATTn + col];
        ushort h, l;
        split_bf(f, h, l);
        size_t idx = (size_t)gid * 8 + i;
        Bhi[idx] = h; Blo[idx] = l;
    }
}

// Stage one quarter-K of B (2 ksteps: hi+lo, 32 KB) into dst.
// Layout: [ks2][hp][512 chunks]; chunk c = i*512 + t.
__device__ __forceinline__ void stage_quarter(
    float4* dst, const ushort* __restrict__ Bhi,
    const ushort* __restrict__ Blo, int q, int t, int w)
{
    #pragma unroll
    for (int i = 0; i < 4; ++i) {
        int c   = i * 512 + t;           // 0..2047
        int ks2 = c >> 10;               // wave-uniform (i>>1)
        int hp  = (c >> 9) & 1;          // wave-uniform (i&1)
        int idx = c & 511;
        const ushort* src = (hp ? Blo : Bhi)
                          + ((size_t)((q * 2 + ks2) * 512 + idx)) * 8;
        gload_lds16(src, dst + (i * 512 + w * 64));
    }
}

// One k-step (K=32): convert kv -> bf16 hi/lo, refill kv ring 4 ahead,
// 8 column fragments x 3 split-MFMAs with a 3-deep circular B prefetch.
// MFMA cluster wrapped in setprio(1) (T5).
template<int KS>
__device__ __forceinline__ void kstep(
    float4* smem, const float* kb,
    float4 (&kv)[4][2], f32x4 (&acc)[NJ], int lane)
{
    const float4* buf = smem + ((KS >> 1) & 1) * 2048;   // quarter buffer
    constexpr int S  = KS & 3;                           // kv ring slot
    constexpr int S2 = KS & 1;                           // kstep within quarter
    short8 ah, al;
    {
        float4 v0 = kv[S][0], v1 = kv[S][1];
        float f[8] = {v0.x, v0.y, v0.z, v0.w, v1.x, v1.y, v1.z, v1.w};
        #pragma unroll
        for (int i = 0; i < 8; ++i) {
            ushort h, l;
            split_bf(f[i], h, l);
            ah[i] = (short)h; al[i] = (short)l;
        }
    }
    if (KS + 4 < 8) {   // 4-deep kv prefetch (stays in flight across barriers)
        kv[S][0] = *(const float4*)(kb + (KS + 4) * 32);
        kv[S][1] = *(const float4*)(kb + (KS + 4) * 32 + 4);
    }
    const float4* Bh = buf + S2 * 1024 + lane;
    const float4* Bl = Bh + 512;
    short8 bh[3], bl[3];
    bh[0] = *(const short8*)(Bh);
    bl[0] = *(const short8*)(Bl);
    bh[1] = *(const short8*)(Bh + 64);
    bl[1] = *(const short8*)(Bl + 64);
    bh[2] = *(const short8*)(Bh + 128);
    bl[2] = *(const short8*)(Bl + 128);
    __builtin_amdgcn_s_setprio(1);
    #pragma unroll
    for (int j = 0; j < NJ; ++j) {
        const int slot = j % 3;          // static after unroll
        short8 cbh = bh[slot], cbl = bl[slot];
        if (j + 3 < NJ) {
            bh[slot] = *(const short8*)(Bh + (j + 3) * 64);
            bl[slot] = *(const short8*)(Bl + (j + 3) * 64);
        }
        acc[j] = MFMA_BF16(ah, cbh, acc[j], 0, 0, 0);
        acc[j] = MFMA_BF16(ah, cbl, acc[j], 0, 0, 0);
        acc[j] = MFMA_BF16(al, cbh, acc[j], 0, 0, 0);
    }
    __builtin_amdgcn_s_setprio(0);
}

// Counted-vmcnt barrier (T4): drain the 4 stage loads (issued FIRST in the
// quarter, order pinned by sched_barrier) but leave the 4 newest kv global
// loads in flight across the barrier. NEVER vmcnt(0) in the main loop.
#define QBARRIER_COUNTED()                                    \
    asm volatile("s_waitcnt vmcnt(4)" ::: "memory");          \
    __builtin_amdgcn_sched_barrier(0);                        \
    __builtin_amdgcn_s_barrier();                             \
    __builtin_amdgcn_sched_barrier(0);

// Fused: scores (bf16-split MFMA, K=256, N=128) + partial weighted sums.
// 8 waves x 16 rows (BM=128). B quarter-K double-buffered (2 x 32 KB),
// next quarter's stage issued BEFORE the current quarter's compute, and
// the quarter barrier is a counted-vmcnt raw s_barrier (kv prefetch never
// drained). 64 KB LDS -> 2 blocks/CU = 16 waves/CU (4/SIMD).
__global__ __launch_bounds__(512)
__attribute__((amdgpu_waves_per_eu(4, 4))) void k_scores(
    const float*  __restrict__ key,
    const ushort* __restrict__ Bhi, const ushort* __restrict__ Blo,
    const float*  __restrict__ bias, const float* __restrict__ u,
    const int*    __restrict__ mask,
    float* __restrict__ P, float* __restrict__ den)
{
    __shared__ float4 smem[4096];        // 64 KB: 2 x 32 KB quarter buffers
    float*  esp   = (float*)smem;        // [128] scores (aliased after loop)
    float4* partp = smem + 64;           // [8][64] float4 partials

    const int t    = threadIdx.x;        // 0..511
    const int lane = t & 63;
    const int w    = t >> 6;             // wave 0..7 -> rows w*16..w*16+15
    const int gb   = blockIdx.x;
    const int row0 = gb * BM;
    const int l15  = lane & 15;
    const int lg   = lane >> 4;

    const float* kb = key + (size_t)(row0 + w * 16 + l15) * Dn + lg * 8;

    f32x4 acc[NJ];
    #pragma unroll
    for (int j = 0; j < NJ; ++j) acc[j] = (f32x4){0.f, 0.f, 0.f, 0.f};

    // kv ring: k-steps 0..3
    float4 kv[4][2];
    #pragma unroll
    for (int s = 0; s < 4; ++s) {
        kv[s][0] = *(const float4*)(kb + s * 32);
        kv[s][1] = *(const float4*)(kb + s * 32 + 4);
    }

    stage_quarter(smem, Bhi, Blo, 0, t, w);          // quarter 0 -> buf0
    __syncthreads();                                 // one-time full drain

    // Q0: stage Q1 first (order pinned), compute ksteps 0-1, counted barrier.
    stage_quarter(smem + 2048, Bhi, Blo, 1, t, w);
    __builtin_amdgcn_sched_barrier(0);
    kstep<0>(smem, kb, kv, acc, lane);
    kstep<1>(smem, kb, kv, acc, lane);
    QBARRIER_COUNTED();                              // drains stage, not kv

    // Q1
    stage_quarter(smem, Bhi, Blo, 2, t, w);
    __builtin_amdgcn_sched_barrier(0);
    kstep<2>(smem, kb, kv, acc, lane);
    kstep<3>(smem, kb, kv, acc, lane);
    QBARRIER_COUNTED();

    // Q2 (stage Q3 is the NEWEST vmem here -> must drain fully)
    stage_quarter(smem + 2048, Bhi, Blo, 3, t, w);
    __builtin_amdgcn_sched_barrier(0);
    kstep<4>(smem, kb, kv, acc, lane);
    kstep<5>(smem, kb, kv, acc, lane);
    asm volatile("s_waitcnt vmcnt(0)" ::: "memory");
    __builtin_amdgcn_sched_barrier(0);
    __builtin_amdgcn_s_barrier();
    __builtin_amdgcn_sched_barrier(0);

    // Q3
    kstep<6>(smem, kb, kv, acc, lane);
    kstep<7>(smem, kb, kv, acc, lane);
    __syncthreads();                     // B dead; smem reusable

    // Epilogue: s(row) = sum_col tanh(acc+bias)*u; e = exp(s)*mask.
    // C/D layout: col = 16j + l15, row(frag-local) = lg*4 + reg.
    float s4[4] = {0.f, 0.f, 0.f, 0.f};
    #pragma unroll
    for (int j = 0; j < NJ; ++j) {
        int col = j * 16 + l15;
        float bv = bias[col], uvv = u[col];
        #pragma unroll
        for (int reg = 0; reg < 4; ++reg)
            s4[reg] += tanh_fast(acc[j][reg] + bv) * uvv;
    }
    #pragma unroll
    for (int reg = 0; reg < 4; ++reg) {
        float s = s4[reg];
        s += __shfl_xor(s, 1);
        s += __shfl_xor(s, 2);
        s += __shfl_xor(s, 4);
        s += __shfl_xor(s, 8);
        if (l15 == 0) {
            int rl = w * 16 + lg * 4 + reg;
            esp[rl] = __builtin_amdgcn_exp2f(s * 1.4426950408889634f)
                      * (float)mask[row0 + rl];
        }
    }
    __syncthreads();

    // block-partial denominator (128 scores)
    if (t < 64) {
        float v = esp[t] + esp[t + 64];
        #pragma unroll
        for (int m = 1; m < 64; m <<= 1) v += __shfl_xor(v, m);
        if (t == 0) den[gb] = v;
    }

    // phase 2: wave w sums its 16 rows over all d (tile is L2/L3-hot).
    {
        const float4* kt = (const float4*)(key + (size_t)(row0 + w * 16) * Dn);
        float4 a2 = make_float4(0.f, 0.f, 0.f, 0.f);
        #pragma unroll 4
        for (int s2 = 0; s2 < 16; ++s2) {
            float wv   = esp[w * 16 + s2];
            float4 kvv = kt[(size_t)s2 * 64 + lane];
            a2.x += wv * kvv.x; a2.y += wv * kvv.y;
            a2.z += wv * kvv.z; a2.w += wv * kvv.w;
        }
        partp[w * 64 + lane] = a2;
    }
    __syncthreads();

    if (t < 64) {
        float4 o = partp[t];
        #pragma unroll
        for (int wv = 1; wv < 8; ++wv) {
            float4 p = partp[wv * 64 + t];
            o.x += p.x; o.y += p.y; o.z += p.z; o.w += p.w;
        }
        *(float4*)(P + (size_t)gb * Dn + t * 4) = o;
    }
}

// combine 8 block-partials per batch, normalize.
__global__ __launch_bounds__(256) void k_final(const float* __restrict__ P,
        const float* __restrict__ den, float* __restrict__ out) {
    int b = blockIdx.x, t = threadIdx.x;
    float dtot = 0.f;
    #pragma unroll
    for (int k = 0; k < 8; ++k) dtot += den[b * 8 + k];
    float o = 0.f;
    #pragma unroll
    for (int k = 0; k < 8; ++k) o += P[(size_t)(b * 8 + k) * Dn + t];
    out[(size_t)b * Dn + t] = o / (dtot + EPS_F);
}

extern "C" void kernel_launch(void* const* d_in, const int* in_sizes, int n_in,
                              void* d_out, int out_size, void* d_ws, size_t ws_size,
                              hipStream_t stream) {
    const float* key   = (const float*)d_in[0];
    const float* query = (const float*)d_in[1];
    const int*   mask  = (const int*)d_in[2];
    const float* W     = (const float*)d_in[3];
    const float* bias  = (const float*)d_in[4];
    const float* Wu    = (const float*)d_in[5];
    float* out = (float*)d_out;

    char* ws = (char*)d_ws;
    float*  u   = (float*)(ws);
    ushort* Bhi = (ushort*)(ws + 512);
    ushort* Blo = (ushort*)(ws + 66048);
    float*  Pp  = (float*)(ws + 131584);
    float*  den = (float*)(ws + 1180160);

    hipLaunchKernelGGL(k_prep,   dim3(17),   dim3(256), 0, stream, Wu, query, u, W, Bhi, Blo);
    hipLaunchKernelGGL(k_scores, dim3(NBLK), dim3(512), 0, stream,
                       key, Bhi, Blo, bias, u, mask, Pp, den);
    hipLaunchKernelGGL(k_final,  dim3(Bn),   dim3(256), 0, stream, Pp, den, out);
}

// Round 15
// 53.553 us; speedup vs baseline: 4.0562x; 1.0668x over previous
//
#include <hip/hip_runtime.h>
#include <hip/hip_bf16.h>
#include <math.h>

#define EPS_F 1e-7f

constexpr int Bn = 128, Sn = 1024, Dn = 256, ATTn = 128, QDn = 128;
constexpr int Mn = Bn * Sn;          // 131072 rows
constexpr int BM = 128;              // rows per block (8 waves x 16 rows)
constexpr int NBLK = Mn / BM;        // 1024 blocks
constexpr int NJ = ATTn / 16;        // 8 column fragments

typedef short short8 __attribute__((ext_vector_type(8)));
typedef float f32x4  __attribute__((ext_vector_type(4)));

// Exact truncation split of A: f = hi + r exactly, lo = bf16_rne(r).
// (ah+al)*bh preserves A to ~2^-17; B carries bf16-RNE error (2^-10).
__device__ inline void split_bf(float f, ushort& hi, ushort& lo) {
    uint fb = __float_as_uint(f);
    hi = (ushort)(fb >> 16);
    float hf = __uint_as_float(fb & 0xffff0000u);
    float lf = f - hf;                       // exact
    __hip_bfloat16 lb = __float2bfloat16(lf);
    __builtin_memcpy(&lo, &lb, 2);
}

__device__ inline float tanh_fast(float x) {
    float cx = fminf(9.0f, fmaxf(-9.0f, x));
    float e = __builtin_amdgcn_exp2f(cx * 2.8853900817779268f);  // e^{2x}
    return (e - 1.0f) * __builtin_amdgcn_rcpf(e + 1.0f);
}

// async global->LDS, 16B per lane. LDS dest is wave-uniform base + lane*16;
// the GLOBAL source is per-lane.
__device__ inline void gload_lds16(const void* g, void* lds_base) {
    __builtin_amdgcn_global_load_lds(
        (const __attribute__((address_space(1))) unsigned int*)g,
        (__attribute__((address_space(3))) unsigned int*)lds_base, 16, 0, 0);
}

#define MFMA_BF16 __builtin_amdgcn_mfma_f32_16x16x32_bf16

// ---------------- ws layout (bytes) ----------------
// [0,512)              u (128 f32)
// [512,66048)          Bhi (4096 chunks x 8 bf16, RNE)
// [66048,1114624)      P   (1024 blk * 256 d f32)
// [1114624,1118720)    den (1024 f32)

// Merged prep: block 0 computes u = W_u @ query; blocks 1..16 build the
// MFMA-B-fragment-ordered bf16 (RNE) copy of W.
// Fragment (ks,j): lane l holds col = 16j+(l&15), k = 32ks+(l>>4)*8+i.
__global__ __launch_bounds__(256) void k_prep(
    const float* __restrict__ Wu, const float* __restrict__ q,
    float* __restrict__ u,
    const float* __restrict__ W,
    ushort* __restrict__ Bhi)
{
    if (blockIdx.x == 0) {
        __shared__ float qs[QDn];
        int t = threadIdx.x;
        if (t < QDn) qs[t] = q[t];
        __syncthreads();
        if (t < ATTn) {
            float acc = 0.f;
            #pragma unroll 8
            for (int j = 0; j < QDn; ++j) acc += Wu[t * QDn + j] * qs[j];
            u[t] = acc;
        }
        return;
    }
    int gid  = (blockIdx.x - 1) * 256 + threadIdx.x;   // 0..4095
    int lane = gid & 63;
    int j    = (gid >> 6) & 7;
    int ks   = gid >> 9;
    int col  = j * 16 + (lane & 15);
    int kb   = ks * 32 + (lane >> 4) * 8;
    #pragma unroll
    for (int i = 0; i < 8; ++i) {
        float f = W[(size_t)(kb + i) * ATTn + col];
        __hip_bfloat16 h = __float2bfloat16(f);   // RNE
        ushort hu; __builtin_memcpy(&hu, &h, 2);
        Bhi[(size_t)gid * 8 + i] = hu;
    }
}

// One k-step (K=32): convert kv -> bf16 hi/lo, refill kv ring 4 ahead,
// 8 column fragments x 2 MFMAs ((ah+al)*bh) with 3-deep circular bh prefetch.
template<int KS>
__device__ __forceinline__ void kstep(
    const float4* smem, const float* kb,
    float4 (&kv)[4][2], f32x4 (&acc)[NJ], int lane)
{
    constexpr int S = KS & 3;                            // kv ring slot
    short8 ah, al;
    {
        float4 v0 = kv[S][0], v1 = kv[S][1];
        float f[8] = {v0.x, v0.y, v0.z, v0.w, v1.x, v1.y, v1.z, v1.w};
        #pragma unroll
        for (int i = 0; i < 8; ++i) {
            ushort h, l;
            split_bf(f[i], h, l);
            ah[i] = (short)h; al[i] = (short)l;
        }
    }
    if (KS + 4 < 8) {   // 4-deep kv prefetch (never drained mid-loop)
        kv[S][0] = *(const float4*)(kb + (KS + 4) * 32);
        kv[S][1] = *(const float4*)(kb + (KS + 4) * 32 + 4);
    }
    const float4* Bh = smem + KS * 512 + lane;
    short8 bh[3];
    bh[0] = *(const short8*)(Bh);
    bh[1] = *(const short8*)(Bh + 64);
    bh[2] = *(const short8*)(Bh + 128);
    __builtin_amdgcn_s_setprio(1);
    #pragma unroll
    for (int j = 0; j < NJ; ++j) {
        const int slot = j % 3;          // static after unroll
        short8 cbh = bh[slot];
        if (j + 3 < NJ)
            bh[slot] = *(const short8*)(Bh + (j + 3) * 64);
        acc[j] = MFMA_BF16(ah, cbh, acc[j], 0, 0, 0);
        acc[j] = MFMA_BF16(al, cbh, acc[j], 0, 0, 0);
    }
    __builtin_amdgcn_s_setprio(0);
}

// Fused: scores ((ah+al)*bh MFMA, K=256, N=128) + partial weighted sums.
// 8 waves x 16 rows (BM=128). FULL Bhi (64 KB) staged to LDS ONCE; the
// whole 8-k-step loop runs with ZERO barriers (B is read-only, waves drift
// freely; kv ring covers HBM latency). 64 KB LDS -> 2 blocks/CU.
__global__ __launch_bounds__(512, 4) void k_scores(
    const float*  __restrict__ key,
    const ushort* __restrict__ Bhi,
    const float*  __restrict__ bias, const float* __restrict__ u,
    const int*    __restrict__ mask,
    float* __restrict__ P, float* __restrict__ den)
{
    __shared__ float4 smem[4096];        // 64 KB: full Bhi; aliased after loop
    float*  esp   = (float*)smem;        // [128] scores (B dead by then)
    float4* partp = smem + 64;           // [8][64] float4 partials

    const int t    = threadIdx.x;        // 0..511
    const int lane = t & 63;
    const int w    = t >> 6;             // wave 0..7 -> rows w*16..w*16+15
    const int gb   = blockIdx.x;
    const int row0 = gb * BM;
    const int l15  = lane & 15;
    const int lg   = lane >> 4;

    const float* kb = key + (size_t)(row0 + w * 16 + l15) * Dn + lg * 8;

    f32x4 acc[NJ];
    #pragma unroll
    for (int j = 0; j < NJ; ++j) acc[j] = (f32x4){0.f, 0.f, 0.f, 0.f};

    // kv ring: k-steps 0..3
    float4 kv[4][2];
    #pragma unroll
    for (int s = 0; s < 4; ++s) {
        kv[s][0] = *(const float4*)(kb + s * 32);
        kv[s][1] = *(const float4*)(kb + s * 32 + 4);
    }

    // stage full Bhi (4096 chunks), linear, 8 chunks/thread
    #pragma unroll
    for (int i = 0; i < 8; ++i)
        gload_lds16(Bhi + (size_t)(i * 512 + t) * 8, smem + (i * 512 + w * 64));
    __syncthreads();                     // one-time drain; B ready

    kstep<0>(smem, kb, kv, acc, lane);
    kstep<1>(smem, kb, kv, acc, lane);
    kstep<2>(smem, kb, kv, acc, lane);
    kstep<3>(smem, kb, kv, acc, lane);
    kstep<4>(smem, kb, kv, acc, lane);
    kstep<5>(smem, kb, kv, acc, lane);
    kstep<6>(smem, kb, kv, acc, lane);
    kstep<7>(smem, kb, kv, acc, lane);
    __syncthreads();                     // all waves done; smem reusable

    // Epilogue: s(row) = sum_col tanh(acc+bias)*u; e = exp(s)*mask.
    // C/D layout: col = 16j + l15, row(frag-local) = lg*4 + reg.
    float s4[4] = {0.f, 0.f, 0.f, 0.f};
    #pragma unroll
    for (int j = 0; j < NJ; ++j) {
        int col = j * 16 + l15;
        float bv = bias[col], uvv = u[col];
        #pragma unroll
        for (int reg = 0; reg < 4; ++reg)
            s4[reg] += tanh_fast(acc[j][reg] + bv) * uvv;
    }
    #pragma unroll
    for (int reg = 0; reg < 4; ++reg) {
        float s = s4[reg];
        s += __shfl_xor(s, 1);
        s += __shfl_xor(s, 2);
        s += __shfl_xor(s, 4);
        s += __shfl_xor(s, 8);
        if (l15 == 0) {
            int rl = w * 16 + lg * 4 + reg;
            esp[rl] = __builtin_amdgcn_exp2f(s * 1.4426950408889634f)
                      * (float)mask[row0 + rl];
        }
    }
    __syncthreads();

    // block-partial denominator (128 scores)
    if (t < 64) {
        float v = esp[t] + esp[t + 64];
        #pragma unroll
        for (int m = 1; m < 64; m <<= 1) v += __shfl_xor(v, m);
        if (t == 0) den[gb] = v;
    }

    // phase 2: wave w sums its 16 rows over all d (tile is L2/L3-hot).
    {
        const float4* kt = (const float4*)(key + (size_t)(row0 + w * 16) * Dn);
        float4 a2 = make_float4(0.f, 0.f, 0.f, 0.f);
        #pragma unroll 4
        for (int s2 = 0; s2 < 16; ++s2) {
            float wv   = esp[w * 16 + s2];
            float4 kvv = kt[(size_t)s2 * 64 + lane];
            a2.x += wv * kvv.x; a2.y += wv * kvv.y;
            a2.z += wv * kvv.z; a2.w += wv * kvv.w;
        }
        partp[w * 64 + lane] = a2;
    }
    __syncthreads();

    if (t < 64) {
        float4 o = partp[t];
        #pragma unroll
        for (int wv = 1; wv < 8; ++wv) {
            float4 p = partp[wv * 64 + t];
            o.x += p.x; o.y += p.y; o.z += p.z; o.w += p.w;
        }
        *(float4*)(P + (size_t)gb * Dn + t * 4) = o;
    }
}

// combine 8 block-partials per batch, normalize.
__global__ __launch_bounds__(256) void k_final(const float* __restrict__ P,
        const float* __restrict__ den, float* __restrict__ out) {
    int b = blockIdx.x, t = threadIdx.x;
    float dtot = 0.f;
    #pragma unroll
    for (int k = 0; k < 8; ++k) dtot += den[b * 8 + k];
    float o = 0.f;
    #pragma unroll
    for (int k = 0; k < 8; ++k) o += P[(size_t)(b * 8 + k) * Dn + t];
    out[(size_t)b * Dn + t] = o / (dtot + EPS_F);
}

extern "C" void kernel_launch(void* const* d_in, const int* in_sizes, int n_in,
                              void* d_out, int out_size, void* d_ws, size_t ws_size,
                              hipStream_t stream) {
    const float* key   = (const float*)d_in[0];
    const float* query = (const float*)d_in[1];
    const int*   mask  = (const int*)d_in[2];
    const float* W     = (const float*)d_in[3];
    const float* bias  = (const float*)d_in[4];
    const float* Wu    = (const float*)d_in[5];
    float* out = (float*)d_out;

    char* ws = (char*)d_ws;
    float*  u   = (float*)(ws);
    ushort* Bhi = (ushort*)(ws + 512);
    float*  Pp  = (float*)(ws + 66048);
    float*  den = (float*)(ws + 1114624);

    hipLaunchKernelGGL(k_prep,   dim3(17),   dim3(256), 0, stream, Wu, query, u, W, Bhi);
    hipLaunchKernelGGL(k_scores, dim3(NBLK), dim3(512), 0, stream,
                       key, Bhi, bias, u, mask, Pp, den);
    hipLaunchKernelGGL(k_final,  dim3(Bn),   dim3(256), 0, stream, Pp, den, out);
}

// Round 16
// 51.900 us; speedup vs baseline: 4.1854x; 1.0318x over previous
//
#include <hip/hip_runtime.h>
#include <hip/hip_bf16.h>
#include <math.h>

#define EPS_F 1e-7f

constexpr int Bn = 128, Sn = 1024, Dn = 256, ATTn = 128, QDn = 128;
constexpr int Mn = Bn * Sn;          // 131072 rows
constexpr int BM = 128;              // rows per block (8 waves x 16 rows)
constexpr int NBLK = Mn / BM;        // 1024 blocks
constexpr int NJ = ATTn / 16;        // 8 column fragments

typedef short short8 __attribute__((ext_vector_type(8)));
typedef float f32x4  __attribute__((ext_vector_type(4)));

// Exact truncation split of A: f = hi + r exactly, lo = bf16_rne(r).
// (ah+al)*bh preserves A to ~2^-17; B carries bf16-RNE error (2^-10).
__device__ inline void split_bf(float f, ushort& hi, ushort& lo) {
    uint fb = __float_as_uint(f);
    hi = (ushort)(fb >> 16);
    float hf = __uint_as_float(fb & 0xffff0000u);
    float lf = f - hf;                       // exact
    __hip_bfloat16 lb = __float2bfloat16(lf);
    __builtin_memcpy(&lo, &lb, 2);
}

__device__ inline float tanh_fast(float x) {
    float cx = fminf(9.0f, fmaxf(-9.0f, x));
    float e = __builtin_amdgcn_exp2f(cx * 2.8853900817779268f);  // e^{2x}
    return (e - 1.0f) * __builtin_amdgcn_rcpf(e + 1.0f);
}

// async global->LDS, 16B per lane. LDS dest is wave-uniform base + lane*16;
// the GLOBAL source is per-lane.
__device__ inline void gload_lds16(const void* g, void* lds_base) {
    __builtin_amdgcn_global_load_lds(
        (const __attribute__((address_space(1))) unsigned int*)g,
        (__attribute__((address_space(3))) unsigned int*)lds_base, 16, 0, 0);
}

#define MFMA_BF16 __builtin_amdgcn_mfma_f32_16x16x32_bf16

// ---------------- ws layout (bytes) ----------------
// [0,512)              u (128 f32)
// [512,66048)          Bhi (4096 chunks x 8 bf16, RNE)
// [66048,1114624)      P   (1024 blk * 256 d f32)
// [1114624,1118720)    den (1024 f32)

// Merged prep: block 0 computes u = W_u @ query; blocks 1..16 build the
// MFMA-B-fragment-ordered bf16 (RNE) copy of W.
// Fragment (ks,j): lane l holds col = 16j+(l&15), k = 32ks+(l>>4)*8+i.
// Chunk index = (ks*8 + j)*64 + lane.
__global__ __launch_bounds__(256) void k_prep(
    const float* __restrict__ Wu, const float* __restrict__ q,
    float* __restrict__ u,
    const float* __restrict__ W,
    ushort* __restrict__ Bhi)
{
    if (blockIdx.x == 0) {
        __shared__ float qs[QDn];
        int t = threadIdx.x;
        if (t < QDn) qs[t] = q[t];
        __syncthreads();
        if (t < ATTn) {
            float acc = 0.f;
            #pragma unroll 8
            for (int j = 0; j < QDn; ++j) acc += Wu[t * QDn + j] * qs[j];
            u[t] = acc;
        }
        return;
    }
    int gid  = (blockIdx.x - 1) * 256 + threadIdx.x;   // 0..4095
    int lane = gid & 63;
    int j    = (gid >> 6) & 7;
    int ks   = gid >> 9;
    int col  = j * 16 + (lane & 15);
    int kb   = ks * 32 + (lane >> 4) * 8;
    #pragma unroll
    for (int i = 0; i < 8; ++i) {
        float f = W[(size_t)(kb + i) * ATTn + col];
        __hip_bfloat16 h = __float2bfloat16(f);   // RNE
        ushort hu; __builtin_memcpy(&hu, &h, 2);
        Bhi[(size_t)gid * 8 + i] = hu;
    }
}

// ---------- k_scores helpers ----------
// LDS map (float4 chunks): B0=[0,1024) B1=[1024,2048) A0=[2048,3072) A1=[3072,4096)

// Stage one B quarter (2 ksteps, 16 KB) into bbuf. Linear, lane-contiguous.
__device__ __forceinline__ void stage_Bq(
    float4* bbuf, const ushort* __restrict__ Bhi, int q, int t, int w)
{
    #pragma unroll
    for (int i = 0; i < 2; ++i) {
        int c = i * 512 + t;             // 0..1023
        gload_lds16(Bhi + (size_t)(q * 1024 + c) * 8, bbuf + (i * 512 + w * 64));
    }
}

// Stage one A tile (128 rows x 32 k f32, 16 KB) into abuf.
// LDS slot s holds logical chunk (row = s>>3, c = (s&7) ^ (row&7)) via
// inverse-swizzled per-lane global SOURCE (linear DMA dest, rule #21).
// Per wave-instruction: 8 full rows x 128 B contiguous line slices.
__device__ __forceinline__ void stage_A(
    float4* abuf, const float* __restrict__ key, int row0, int ks, int t, int w)
{
    #pragma unroll
    for (int i = 0; i < 2; ++i) {
        int s   = i * 512 + t;           // 0..1023
        int row = s >> 3;
        int cl  = (s & 7) ^ (row & 7);
        const float* src = key + (size_t)(row0 + row) * Dn + ks * 32 + cl * 4;
        gload_lds16(src, abuf + (i * 512 + w * 64));
    }
}

// One k-step: A fragment from LDS (swizzled read) -> split bf16 hi/lo,
// 8 column fragments x 2 MFMAs with 3-deep circular bh prefetch.
template<int KS>
__device__ __forceinline__ void compute_ks(
    const float4* abuf, const float4* bbuf,
    f32x4 (&acc)[NJ], int w, int lane)
{
    const int l15 = lane & 15, lg = lane >> 4;
    const int r = w * 16 + l15;
    float4 a0 = abuf[r * 8 + ((lg * 2)     ^ (r & 7))];
    float4 a1 = abuf[r * 8 + ((lg * 2 + 1) ^ (r & 7))];
    short8 ah, al;
    {
        float f[8] = {a0.x, a0.y, a0.z, a0.w, a1.x, a1.y, a1.z, a1.w};
        #pragma unroll
        for (int i = 0; i < 8; ++i) {
            ushort h, l;
            split_bf(f[i], h, l);
            ah[i] = (short)h; al[i] = (short)l;
        }
    }
    const float4* Bh = bbuf + (KS & 1) * 512 + lane;
    short8 bh[3];
    bh[0] = *(const short8*)(Bh);
    bh[1] = *(const short8*)(Bh + 64);
    bh[2] = *(const short8*)(Bh + 128);
    __builtin_amdgcn_s_setprio(1);
    #pragma unroll
    for (int j = 0; j < NJ; ++j) {
        const int slot = j % 3;          // static after unroll
        short8 cbh = bh[slot];
        if (j + 3 < NJ)
            bh[slot] = *(const short8*)(Bh + (j + 3) * 64);
        acc[j] = MFMA_BF16(ah, cbh, acc[j], 0, 0, 0);
        acc[j] = MFMA_BF16(al, cbh, acc[j], 0, 0, 0);
    }
    __builtin_amdgcn_s_setprio(0);
}

#define PIN() __builtin_amdgcn_sched_barrier(0)

// Fused scores + partial weighted sums. ALL key traffic via global_load_lds
// with line-contiguous sources; waves touch only LDS in the hot loop.
// A tiles (16 KB) double-buffered per kstep; B quarters (16 KB) double-
// buffered, staged 2 ksteps ahead. 64 KB LDS -> 2 blocks/CU (16 waves/CU).
__global__ __launch_bounds__(512, 4) void k_scores(
    const float*  __restrict__ key,
    const ushort* __restrict__ Bhi,
    const float*  __restrict__ bias, const float* __restrict__ u,
    const int*    __restrict__ mask,
    float* __restrict__ P, float* __restrict__ den)
{
    __shared__ float4 smem[4096];        // 64 KB
    float4* B0 = smem;
    float4* B1 = smem + 1024;
    float4* A0 = smem + 2048;
    float4* A1 = smem + 3072;
    float*  esp   = (float*)smem;        // [128] scores (aliased after loop)
    float4* partp = smem + 64;           // [8][64] float4 partials

    const int t    = threadIdx.x;        // 0..511
    const int lane = t & 63;
    const int w    = t >> 6;             // wave 0..7 -> rows w*16..w*16+15
    const int gb   = blockIdx.x;
    const int row0 = gb * BM;
    const int l15  = lane & 15;
    const int lg   = lane >> 4;

    f32x4 acc[NJ];
    #pragma unroll
    for (int j = 0; j < NJ; ++j) acc[j] = (f32x4){0.f, 0.f, 0.f, 0.f};

    // prologue: B quarter 0 + A tile 0
    stage_Bq(B0, Bhi, 0, t, w);
    stage_A(A0, key, row0, 0, t, w);
    __syncthreads();

    // ks0: stage Bq1 + A1, compute(A0,B0)
    stage_Bq(B1, Bhi, 1, t, w);
    stage_A(A1, key, row0, 1, t, w);
    PIN();
    compute_ks<0>(A0, B0, acc, w, lane);
    __syncthreads();
    // ks1
    stage_A(A0, key, row0, 2, t, w);
    PIN();
    compute_ks<1>(A1, B0, acc, w, lane);
    __syncthreads();
    // ks2: B0 free (ks0/ks1 done) -> stage Bq2
    stage_Bq(B0, Bhi, 2, t, w);
    stage_A(A1, key, row0, 3, t, w);
    PIN();
    compute_ks<2>(A0, B1, acc, w, lane);
    __syncthreads();
    // ks3
    stage_A(A0, key, row0, 4, t, w);
    PIN();
    compute_ks<3>(A1, B1, acc, w, lane);
    __syncthreads();
    // ks4: B1 free -> stage Bq3
    stage_Bq(B1, Bhi, 3, t, w);
    stage_A(A1, key, row0, 5, t, w);
    PIN();
    compute_ks<4>(A0, B0, acc, w, lane);
    __syncthreads();
    // ks5
    stage_A(A0, key, row0, 6, t, w);
    PIN();
    compute_ks<5>(A1, B0, acc, w, lane);
    __syncthreads();
    // ks6
    stage_A(A1, key, row0, 7, t, w);
    PIN();
    compute_ks<6>(A0, B1, acc, w, lane);
    __syncthreads();
    // ks7
    compute_ks<7>(A1, B1, acc, w, lane);
    __syncthreads();                     // smem dead; reusable

    // Epilogue: s(row) = sum_col tanh(acc+bias)*u; e = exp(s)*mask.
    // C/D layout: col = 16j + l15, row(frag-local) = lg*4 + reg.
    float s4[4] = {0.f, 0.f, 0.f, 0.f};
    #pragma unroll
    for (int j = 0; j < NJ; ++j) {
        int col = j * 16 + l15;
        float bv = bias[col], uvv = u[col];
        #pragma unroll
        for (int reg = 0; reg < 4; ++reg)
            s4[reg] += tanh_fast(acc[j][reg] + bv) * uvv;
    }
    #pragma unroll
    for (int reg = 0; reg < 4; ++reg) {
        float s = s4[reg];
        s += __shfl_xor(s, 1);
        s += __shfl_xor(s, 2);
        s += __shfl_xor(s, 4);
        s += __shfl_xor(s, 8);
        if (l15 == 0) {
            int rl = w * 16 + lg * 4 + reg;
            esp[rl] = __builtin_amdgcn_exp2f(s * 1.4426950408889634f)
                      * (float)mask[row0 + rl];
        }
    }
    __syncthreads();

    // block-partial denominator (128 scores)
    if (t < 64) {
        float v = esp[t] + esp[t + 64];
        #pragma unroll
        for (int m = 1; m < 64; m <<= 1) v += __shfl_xor(v, m);
        if (t == 0) den[gb] = v;
    }

    // phase 2: wave w sums its 16 rows over all d (tile is L2/L3-hot;
    // lane-contiguous reads).
    {
        const float4* kt = (const float4*)(key + (size_t)(row0 + w * 16) * Dn);
        float4 a2 = make_float4(0.f, 0.f, 0.f, 0.f);
        #pragma unroll 4
        for (int s2 = 0; s2 < 16; ++s2) {
            float wv   = esp[w * 16 + s2];
            float4 kvv = kt[(size_t)s2 * 64 + lane];
            a2.x += wv * kvv.x; a2.y += wv * kvv.y;
            a2.z += wv * kvv.z; a2.w += wv * kvv.w;
        }
        partp[w * 64 + lane] = a2;
    }
    __syncthreads();

    if (t < 64) {
        float4 o = partp[t];
        #pragma unroll
        for (int wv = 1; wv < 8; ++wv) {
            float4 p = partp[wv * 64 + t];
            o.x += p.x; o.y += p.y; o.z += p.z; o.w += p.w;
        }
        *(float4*)(P + (size_t)gb * Dn + t * 4) = o;
    }
}

// combine 8 block-partials per batch, normalize.
__global__ __launch_bounds__(256) void k_final(const float* __restrict__ P,
        const float* __restrict__ den, float* __restrict__ out) {
    int b = blockIdx.x, t = threadIdx.x;
    float dtot = 0.f;
    #pragma unroll
    for (int k = 0; k < 8; ++k) dtot += den[b * 8 + k];
    float o = 0.f;
    #pragma unroll
    for (int k = 0; k < 8; ++k) o += P[(size_t)(b * 8 + k) * Dn + t];
    out[(size_t)b * Dn + t] = o / (dtot + EPS_F);
}

extern "C" void kernel_launch(void* const* d_in, const int* in_sizes, int n_in,
                              void* d_out, int out_size, void* d_ws, size_t ws_size,
                              hipStream_t stream) {
    const float* key   = (const float*)d_in[0];
    const float* query = (const float*)d_in[1];
    const int*   mask  = (const int*)d_in[2];
    const float* W     = (const float*)d_in[3];
    const float* bias  = (const float*)d_in[4];
    const float* Wu    = (const float*)d_in[5];
    float* out = (float*)d_out;

    char* ws = (char*)d_ws;
    float*  u   = (float*)(ws);
    ushort* Bhi = (ushort*)(ws + 512);
    float*  Pp  = (float*)(ws + 66048);
    float*  den = (float*)(ws + 1114624);

    hipLaunchKernelGGL(k_prep,   dim3(17),   dim3(256), 0, stream, Wu, query, u, W, Bhi);
    hipLaunchKernelGGL(k_scores, dim3(NBLK), dim3(512), 0, stream,
                       key, Bhi, bias, u, mask, Pp, den);
    hipLaunchKernelGGL(k_final,  dim3(Bn),   dim3(256), 0, stream, Pp, den, out);
}